// Round 1
// baseline (937.082 us; speedup 1.0000x reference)
//
#include <hip/hip_runtime.h>

typedef unsigned short u16;
typedef __attribute__((ext_vector_type(8))) __bf16 bf16x8;
typedef __attribute__((ext_vector_type(4))) float f32x4;

static __device__ __forceinline__ u16 f2bf(float f) {
    unsigned u = __float_as_uint(f);
    u += 0x7fffu + ((u >> 16) & 1u);   // round-to-nearest-even
    return (u16)(u >> 16);
}
static __device__ __forceinline__ float bf2f(u16 v) {
    return __uint_as_float(((unsigned)v) << 16);
}

// ---------------- CSR build ----------------

__global__ void hist_k(const int* __restrict__ row, int* __restrict__ cnt, int E) {
    int i = blockIdx.x * blockDim.x + threadIdx.x;
    int stride = gridDim.x * blockDim.x;
    for (; i < E; i += stride) atomicAdd(&cnt[row[i]], 1);
}

__global__ void scan1_k(const int* __restrict__ cnt, int* __restrict__ bsum) {
    int b = blockIdx.x, tid = threadIdx.x;
    int4 v = *(const int4*)&cnt[b * 1024 + tid * 4];
    int s = v.x + v.y + v.z + v.w;
    #pragma unroll
    for (int d = 1; d < 64; d <<= 1) s += __shfl_xor(s, d);
    __shared__ int ws[4];
    if ((tid & 63) == 0) ws[tid >> 6] = s;
    __syncthreads();
    if (tid == 0) bsum[b] = ws[0] + ws[1] + ws[2] + ws[3];
}

__global__ void scan2_k(const int* __restrict__ bsum, int* __restrict__ boff,
                        int* __restrict__ rp, int n, int nblk) {
    __shared__ int s[128];
    int tid = threadIdx.x;
    int v = (tid < nblk) ? bsum[tid] : 0;
    s[tid] = v;
    __syncthreads();
    for (int d = 1; d < 128; d <<= 1) {
        int t = (tid >= d) ? s[tid - d] : 0;
        __syncthreads();
        s[tid] += t;
        __syncthreads();
    }
    if (tid < nblk) boff[tid] = s[tid] - v;
    if (tid == 127) rp[n] = s[127];
}

__global__ void scan3_k(const int* __restrict__ cnt, const int* __restrict__ boff,
                        int* __restrict__ rp, int* __restrict__ nxt, int n) {
    int b = blockIdx.x, tid = threadIdx.x;
    int4 v = *(const int4*)&cnt[b * 1024 + tid * 4];
    int ts = v.x + v.y + v.z + v.w;
    __shared__ int s[256];
    s[tid] = ts;
    __syncthreads();
    for (int d = 1; d < 256; d <<= 1) {
        int t = (tid >= d) ? s[tid - d] : 0;
        __syncthreads();
        s[tid] += t;
        __syncthreads();
    }
    int base = boff[b] + s[tid] - ts;
    int idx = b * 1024 + tid * 4;
    int c[4] = {v.x, v.y, v.z, v.w};
    #pragma unroll
    for (int j = 0; j < 4; ++j) {
        if (idx + j < n) { rp[idx + j] = base; nxt[idx + j] = base; }
        base += c[j];
    }
}

__global__ void scatter_k(const int* __restrict__ row, const int* __restrict__ col,
                          const float* __restrict__ w, int* __restrict__ nxt,
                          int2* __restrict__ colw, int E) {
    int i = blockIdx.x * blockDim.x + threadIdx.x;
    int stride = gridDim.x * blockDim.x;
    for (; i < E; i += stride) {
        int r = row[i];
        int pos = atomicAdd(&nxt[r], 1);
        colw[pos] = make_int2(col[i], __float_as_int(w[i]));
    }
}

// ---------------- weight transpose+convert: W[K][N] f32 -> WT[N][K] bf16 ----------------

__global__ void transpose_w(const float* __restrict__ W, u16* __restrict__ WT, int K, int N) {
    int i = blockIdx.x * blockDim.x + threadIdx.x;
    if (i < K * N) {
        int k = i / N, nn = i % N;
        WT[nn * K + k] = f2bf(W[i]);
    }
}

// ---------------- GEMM: C[M][N] (bf16) = A[M][K] * BT[N][K]^T ----------------
// 128x128 tile, 4 waves (2x2), each wave 64x64 = 4x4 frags of 16x16x32 bf16 MFMA.

template <bool A_IS_F32>
__global__ __launch_bounds__(256) void gemm_bt(const void* __restrict__ Ap,
                                               const u16* __restrict__ BT,
                                               u16* __restrict__ C, int M, int N, int K) {
    __shared__ alignas(16) u16 As[128][40];  // pad 40: 80B row stride -> ~2-way LDS aliasing (free)
    __shared__ alignas(16) u16 Bs[128][40];
    const int tid = threadIdx.x;
    const int lane = tid & 63, wv = tid >> 6;
    const int wm = wv >> 1, wn = wv & 1;
    const int lr = lane & 15, lg = lane >> 4;
    f32x4 acc[4][4] = {};
    const int srow = tid >> 1;
    const int sk = (tid & 1) * 16;
    const long ga_row = (long)blockIdx.x * 128 + srow;
    const long gb_row = (long)blockIdx.y * 128 + srow;
    const float* Af = (const float*)Ap;
    const u16* Ab = (const u16*)Ap;

    for (int kt = 0; kt < K; kt += 32) {
        // ---- stage A (convert f32->bf16 if needed) ----
        if constexpr (A_IS_F32) {
            alignas(16) float fv[16];
            if (ga_row < M) {
                const float* src = Af + ga_row * (long)K + kt + sk;
                *(float4*)&fv[0]  = *(const float4*)(src + 0);
                *(float4*)&fv[4]  = *(const float4*)(src + 4);
                *(float4*)&fv[8]  = *(const float4*)(src + 8);
                *(float4*)&fv[12] = *(const float4*)(src + 12);
            } else {
                #pragma unroll
                for (int j = 0; j < 16; ++j) fv[j] = 0.f;
            }
            alignas(16) u16 tmp[16];
            #pragma unroll
            for (int j = 0; j < 16; ++j) tmp[j] = f2bf(fv[j]);
            *(int4*)&As[srow][sk]     = *(const int4*)&tmp[0];
            *(int4*)&As[srow][sk + 8] = *(const int4*)&tmp[8];
        } else {
            int4 u0, u1;
            if (ga_row < M) {
                const u16* src = Ab + ga_row * (long)K + kt + sk;
                u0 = *(const int4*)src;
                u1 = *(const int4*)(src + 8);
            } else {
                u0 = make_int4(0, 0, 0, 0);
                u1 = make_int4(0, 0, 0, 0);
            }
            *(int4*)&As[srow][sk]     = u0;
            *(int4*)&As[srow][sk + 8] = u1;
        }
        // ---- stage B (always bf16, rows always in-range: N multiple of 128) ----
        {
            const u16* src = BT + gb_row * (long)K + kt + sk;
            *(int4*)&Bs[srow][sk]     = *(const int4*)src;
            *(int4*)&Bs[srow][sk + 8] = *(const int4*)(src + 8);
        }
        __syncthreads();

        bf16x8 a[4], b[4];
        #pragma unroll
        for (int mi = 0; mi < 4; ++mi) a[mi] = *(const bf16x8*)&As[wm * 64 + mi * 16 + lr][lg * 8];
        #pragma unroll
        for (int ni = 0; ni < 4; ++ni) b[ni] = *(const bf16x8*)&Bs[wn * 64 + ni * 16 + lr][lg * 8];
        #pragma unroll
        for (int mi = 0; mi < 4; ++mi)
            #pragma unroll
            for (int ni = 0; ni < 4; ++ni)
                acc[mi][ni] = __builtin_amdgcn_mfma_f32_16x16x32_bf16(a[mi], b[ni], acc[mi][ni], 0, 0, 0);
        __syncthreads();
    }

    // ---- epilogue: C/D layout col=lane&15, row=(lane>>4)*4+j ----
    #pragma unroll
    for (int mi = 0; mi < 4; ++mi) {
        #pragma unroll
        for (int j = 0; j < 4; ++j) {
            long r = (long)blockIdx.x * 128 + wm * 64 + mi * 16 + lg * 4 + j;
            if (r < M) {
                #pragma unroll
                for (int ni = 0; ni < 4; ++ni) {
                    C[r * (long)N + blockIdx.y * 128 + wn * 64 + ni * 16 + lr] = f2bf(acc[mi][ni][j]);
                }
            }
        }
    }
}

// ---------------- SpMM (CSR) + bias + leaky ----------------
// one wave per row; lane owns D/64 dims; gather support rows (bf16), fp32 accum.

template <int D, bool OUT_BF16>
__global__ __launch_bounds__(256) void spmm_k(const int* __restrict__ rp,
                                              const int2* __restrict__ colw,
                                              const u16* __restrict__ sup,
                                              const float* __restrict__ bias,
                                              u16* __restrict__ obf,
                                              float* __restrict__ of32, int n) {
    int wid = blockIdx.x * 4 + (threadIdx.x >> 6);
    if (wid >= n) return;
    int lane = threadIdx.x & 63;
    constexpr int V = D / 64;
    float acc[V];
    #pragma unroll
    for (int j = 0; j < V; ++j) acc[j] = 0.f;
    int e0 = rp[wid], e1 = rp[wid + 1];
    int2 cw;
    if (e0 < e1) cw = colw[e0];
    for (int e = e0; e < e1; ++e) {
        int2 cur = cw;
        if (e + 1 < e1) cw = colw[e + 1];  // prefetch next edge
        float wgt = __int_as_float(cur.y);
        const u16* s = sup + (size_t)cur.x * D + lane * V;
        if constexpr (V == 4) {
            ushort4 v = *(const ushort4*)s;
            acc[0] += wgt * bf2f(v.x);
            acc[1] += wgt * bf2f(v.y);
            acc[2] += wgt * bf2f(v.z);
            acc[3] += wgt * bf2f(v.w);
        } else {
            ushort2 v = *(const ushort2*)s;
            acc[0] += wgt * bf2f(v.x);
            acc[1] += wgt * bf2f(v.y);
        }
    }
    #pragma unroll
    for (int j = 0; j < V; ++j) {
        float h = acc[j] + bias[lane * V + j];
        h = h > 0.f ? h : 0.25f * h;
        if constexpr (OUT_BF16) obf[(size_t)wid * D + lane * V + j] = f2bf(h);
        else                    of32[(size_t)wid * D + lane * V + j] = h;
    }
}

// ---------------- launch ----------------

extern "C" void kernel_launch(void* const* d_in, const int* in_sizes, int n_in,
                              void* d_out, int out_size, void* d_ws, size_t ws_size,
                              hipStream_t stream) {
    const float* x  = (const float*)d_in[0];
    const float* W1 = (const float*)d_in[1];
    const float* b1 = (const float*)d_in[2];
    const float* W2 = (const float*)d_in[3];
    const float* b2 = (const float*)d_in[4];
    const int* arow = (const int*)d_in[5];
    const int* acol = (const int*)d_in[6];
    const float* ew = (const float*)d_in[7];

    const int IN = 512, H = 256, OUT = 128;
    const int n = in_sizes[0] / IN;   // 100000
    const int E = in_sizes[5];        // 3200000
    const int NBLK = (n + 1023) / 1024;

    char* base = (char*)d_ws;
    size_t off = 0;
    auto carve = [&](size_t bytes) -> void* {
        void* r = base + off;
        off = (off + bytes + 255) & ~(size_t)255;
        return r;
    };
    int*  cnt  = (int*)carve((size_t)NBLK * 1024 * 4);
    int*  rp   = (int*)carve((size_t)(n + 1) * 4);
    int*  nxt  = (int*)carve((size_t)n * 4);
    int*  bsum = (int*)carve(512);
    int*  boff = (int*)carve(512);
    int2* colw = (int2*)carve((size_t)E * 8);
    u16*  W1T  = (u16*)carve((size_t)H * IN * 2);
    u16*  W2T  = (u16*)carve((size_t)OUT * H * 2);
    u16*  sup  = (u16*)carve((size_t)n * H * 2);   // support1 [n][256]; reused as support2 [n][128]
    u16*  h1   = (u16*)carve((size_t)n * H * 2);

    // CSR build
    hipMemsetAsync(cnt, 0, (size_t)NBLK * 1024 * 4, stream);
    hist_k<<<2048, 256, 0, stream>>>(arow, cnt, E);
    scan1_k<<<NBLK, 256, 0, stream>>>(cnt, bsum);
    scan2_k<<<1, 128, 0, stream>>>(bsum, boff, rp, n, NBLK);
    scan3_k<<<NBLK, 256, 0, stream>>>(cnt, boff, rp, nxt, n);
    scatter_k<<<2048, 256, 0, stream>>>(arow, acol, ew, nxt, colw, E);

    // weights
    transpose_w<<<(IN * H + 255) / 256, 256, 0, stream>>>(W1, W1T, IN, H);
    transpose_w<<<(H * OUT + 255) / 256, 256, 0, stream>>>(W2, W2T, H, OUT);

    // layer 1
    dim3 g1((n + 127) / 128, H / 128);
    gemm_bt<true><<<g1, 256, 0, stream>>>(x, W1T, sup, n, H, IN);
    spmm_k<256, true><<<(n + 3) / 4, 256, 0, stream>>>(rp, colw, sup, b1, h1, nullptr, n);

    // layer 2
    dim3 g2((n + 127) / 128, OUT / 128);
    gemm_bt<false><<<g2, 256, 0, stream>>>(h1, W2T, sup, n, OUT, H);
    spmm_k<128, false><<<(n + 3) / 4, 256, 0, stream>>>(rp, colw, sup, b2, nullptr, (float*)d_out, n);
}